// Round 17
// baseline (7281.096 us; speedup 1.0000x reference)
//
#include <hip/hip_runtime.h>

#define T_STEPS 2048
#define NWG 256

typedef __bf16 bf16x8 __attribute__((ext_vector_type(8)));
typedef float f32x4 __attribute__((ext_vector_type(4)));
typedef unsigned long long u64;

// ws layout
#define XBF_OFF   0ull                        // [2048][32][256] bf16 = 33554432 B
#define FLAGS_OFF 33554432ull                 // 8 grp x 32 u32 = 1024 B
#define XSLOT_OFF (FLAGS_OFF + 1024ull)       // 256 u32 = 1024 B
#define HBUF_OFF  (XSLOT_OFF + 1024ull)       // 8 grp x 2 buf x 8192 B = 131072 B
#define WS_NEEDED (HBUF_OFF + 131072ull)      // = 33687552 (< proven 33689600)

__device__ __forceinline__ unsigned short f2bf(float f) {
    unsigned int u = __builtin_bit_cast(unsigned int, f);
    u = u + 0x7fffu + ((u >> 16) & 1u);
    return (unsigned short)(u >> 16);
}
__device__ __forceinline__ float sigf(float x) { return 1.0f / (1.0f + __expf(-x)); }
__device__ __forceinline__ float tanhfast(float x) { return 1.0f - 2.0f / (__expf(2.0f * x) + 1.0f); }

// X: [32][2048][256] fp32 -> Xbf: [2048][32][256] bf16
__global__ void prep_x(const float* __restrict__ X, unsigned short* __restrict__ Xbf) {
    unsigned int idx = blockIdx.x * 256u + threadIdx.x;
    unsigned int k4 = idx & 63u;
    unsigned int b  = (idx >> 6) & 31u;
    unsigned int t  = idx >> 11;
    float4 v = *(const float4*)(X + ((size_t)b * 2048u + t) * 256u + k4 * 4u);
    u64 pk = (u64)f2bf(v.x)
           | ((u64)f2bf(v.y) << 16)
           | ((u64)f2bf(v.z) << 32)
           | ((u64)f2bf(v.w) << 48);
    *(u64*)(Xbf + ((size_t)t * 32u + b) * 256u + k4 * 4u) = pk;
}

// 256 WGs = 8 groups (XCD-candidate) x 32 col-slices.
// group = wg&7: dir = grp&1, batch-group = grp>>1 (8 batches each).
__global__ __launch_bounds__(256, 1) void lstm_rec(
    const unsigned short* __restrict__ Xbf,
    const float* __restrict__ W_f, const float* __restrict__ U_f, const float* __restrict__ b_f,
    const float* __restrict__ W_b, const float* __restrict__ U_b, const float* __restrict__ b_b,
    float* __restrict__ out, unsigned int* flags, unsigned int* xslot, u64* Hbuf)
{
    const int wg  = blockIdx.x;
    const int grp = wg & 7;
    const int s   = wg >> 3;        // col-slice 0..31
    const int d   = grp & 1;
    const int bo  = (grp >> 1) * 8; // batch offset
    const int c0  = s * 16;
    const int tid = threadIdx.x;

    const float* Wm = d ? W_b : W_f;
    const float* Um = d ? U_b : U_f;
    const float* bia = d ? b_b : b_f;

    __shared__ __align__(16) unsigned char s_u[65536];   // U slice [64 cols][512 k] bf16, swizzled
    __shared__ __align__(16) unsigned char s_w[32768];   // W slice [64 cols][256 k] bf16, swizzled
    __shared__ __align__(16) unsigned char s_h[16384];   // H stage [16 rows][512 k] bf16 (rows 8..15 zero)
    __shared__ __align__(16) unsigned char s_x[8192];    // X stage [16 rows][256 k] bf16 (rows 8..15 zero)
    __shared__ float s_S[8][64];
    __shared__ float s_bias[64];
    __shared__ int s_abort;
    __shared__ int s_local;

    // ---- prologue ----
    {
        int cl = tid & 15, g = (tid >> 4) & 3, k0 = tid >> 6;
        int n = g * 16 + cl;
        int gcol = g * 512 + c0 + cl;
        for (int i = 0; i < 128; ++i) {
            int k = k0 + i * 4;
            unsigned short v = f2bf(Um[(size_t)k * 2048 + gcol]);
            unsigned int addr = (unsigned)(n * 1024 + k * 2) ^ (unsigned)((n & 7) << 4);
            *(unsigned short*)(s_u + addr) = v;
        }
        for (int i = 0; i < 64; ++i) {
            int k = k0 + i * 4;
            unsigned short v = f2bf(Wm[(size_t)k * 2048 + gcol]);
            unsigned int addr = (unsigned)(n * 512 + k * 2) ^ (unsigned)((n & 7) << 4);
            *(unsigned short*)(s_w + addr) = v;
        }
        if (tid < 64) s_bias[tid] = bia[(tid >> 4) * 512 + c0 + (tid & 15)];
        if (tid == 0) { s_abort = 0; }
        // zero s_h (16 KB) and s_x (8 KB): zeros are swizzle-invariant
        for (int i = 0; i < 8; ++i) *(u64*)(s_h + (tid + i * 256) * 8) = 0ull;
        for (int i = 0; i < 4; ++i) *(u64*)(s_x + (tid + i * 256) * 8) = 0ull;
        // stage x(first) for this group's 8 batches
        int t_x = d ? (T_STEPS - 1) : 0;
        const u64* xb = (const u64*)Xbf + (size_t)t_x * 2048;   // [32][64] u64 per t
        for (int i = 0; i < 2; ++i) {
            int j = tid + i * 256;            // 0..511
            int b = j >> 6, c = j & 63;
            u64 v = xb[(bo + b) * 64 + c];
            unsigned int addr = (unsigned)(b * 512 + c * 8) ^ (unsigned)((b & 7) << 4);
            *(u64*)(s_x + addr) = v;
        }
        // one-time XCC_ID exchange (device scope; deadlock-free: store precedes wait)
        if (tid == 0) {
            unsigned int xcc = 0;
            asm volatile("s_getreg_b32 %0, hwreg(HW_REG_XCC_ID)" : "=s"(xcc));
            __hip_atomic_store(&xslot[wg], xcc + 1u, __ATOMIC_RELAXED, __HIP_MEMORY_SCOPE_AGENT);
        }
        {
            int l = tid & 63;
            unsigned int spin = 0;
            unsigned int vm, v0;
            for (;;) {
                vm = __hip_atomic_load(&xslot[grp + 8 * (l & 31)], __ATOMIC_RELAXED, __HIP_MEMORY_SCOPE_AGENT);
                v0 = __hip_atomic_load(&xslot[grp], __ATOMIC_RELAXED, __HIP_MEMORY_SCOPE_AGENT);
                if (__all((int)(vm != 0u))) break;
                if (++spin > (1u << 21)) { s_abort = 1; break; }
                __builtin_amdgcn_s_sleep(1);
            }
            int loc = __all((int)(vm != 0u && vm == v0)) ? 1 : 0;
            if (tid == 0) s_local = loc;
        }
    }
    __syncthreads();
    if (s_abort) return;
    const bool isLocal = (s_local != 0);

    // per-thread MFMA addressing (16x16x32 bf16)
    const int g  = tid >> 6;          // wave == gate
    const int l  = tid & 63;
    const int cl = l & 15;
    const int h4 = l >> 4;
    const int n  = g * 16 + cl;
    const unsigned int uO = (unsigned)(n * 1024 + h4 * 16);
    const unsigned int wO = (unsigned)(n * 512  + h4 * 16);
    const unsigned int nS = (unsigned)((n & 7) << 4);
    const int b0 = cl;                               // batch row (rows 8..15 are zero-pad)
    const unsigned int hO0 = (unsigned)(b0 * 1024 + h4 * 16);
    const unsigned int xO0 = (unsigned)(b0 * 512  + h4 * 16);
    const unsigned int bS0 = (unsigned)((b0 & 7) << 4);

    // flags: 32 per group, one 128B region
    const unsigned int fBase  = (unsigned)(grp * 32);
    const unsigned int myFlag = fBase + (unsigned)s;
    const unsigned int pollA  = fBase + (unsigned)(l & 15);
    const unsigned int pollB  = fBase + 16u + (unsigned)(l & 15);

    // elementwise mapping (tid<64): batch eb (0..7), local h-cols ecp, ecp+1
    const int eb  = tid >> 3;
    const int ecp = (tid & 7) * 2;
    float c_reg[2] = {0.f, 0.f};

    unsigned int* H32 = (unsigned int*)Hbuf;

    // ---- pin loop-invariant B fragments ----
    bf16x8 wBr[8];
    #pragma unroll
    for (int kc = 0; kc < 8; ++kc)
        wBr[kc] = *(const bf16x8*)(s_w + ((wO + kc * 64) ^ nS));
    bf16x8 uBr[16];
    #pragma unroll
    for (int kc = 0; kc < 16; ++kc)
        uBr[kc] = *(const bf16x8*)(s_u + ((uO + kc * 64) ^ nS));

    // ---- accX(0) ----
    f32x4 axc0 = {0.f, 0.f, 0.f, 0.f};
    #pragma unroll
    for (int kc = 0; kc < 8; ++kc) {
        bf16x8 a0 = *(const bf16x8*)(s_x + ((xO0 + kc * 64) ^ bS0));
        axc0 = __builtin_amdgcn_mfma_f32_16x16x32_bf16(a0, wBr[kc], axc0, 0, 0, 0);
    }

    for (int t = 0; t < T_STEPS; ++t) {
        f32x4 acc0 = axc0;

        if (t > 0) {
            const size_t base64 = (size_t)(grp * 2 + (t & 1)) * 1024;

            // poll half A
            {
                unsigned int spin = 0;
                for (;;) {
                    unsigned int v = isLocal ? *(volatile unsigned int*)&flags[pollA]
                        : __hip_atomic_load(&flags[pollA], __ATOMIC_RELAXED, __HIP_MEMORY_SCOPE_AGENT);
                    if (__all((int)(v >= (unsigned)t))) break;
                    if (++spin > (1u << 21)) { s_abort = 1; break; }
                    if (spin > 64) __builtin_amdgcn_s_sleep(1);
                }
            }
            u64 ra[2];
            #pragma unroll
            for (int i = 0; i < 2; ++i) {
                int j = tid + i * 256; int b = j >> 6, c = j & 63;
                size_t idx = base64 + (size_t)(b * 128 + c);
                ra[i] = isLocal ? *(const volatile u64*)&Hbuf[idx]
                    : __hip_atomic_load(&Hbuf[idx], __ATOMIC_RELAXED, __HIP_MEMORY_SCOPE_AGENT);
            }
            // poll half B
            {
                unsigned int spin = 0;
                for (;;) {
                    unsigned int v = isLocal ? *(volatile unsigned int*)&flags[pollB]
                        : __hip_atomic_load(&flags[pollB], __ATOMIC_RELAXED, __HIP_MEMORY_SCOPE_AGENT);
                    if (__all((int)(v >= (unsigned)t))) break;
                    if (++spin > (1u << 21)) { s_abort = 1; break; }
                    if (spin > 64) __builtin_amdgcn_s_sleep(1);
                }
            }
            u64 rb[2];
            #pragma unroll
            for (int i = 0; i < 2; ++i) {
                int j = tid + i * 256; int b = j >> 6, c = j & 63;
                size_t idx = base64 + (size_t)(b * 128 + 64 + c);
                rb[i] = isLocal ? *(const volatile u64*)&Hbuf[idx]
                    : __hip_atomic_load(&Hbuf[idx], __ATOMIC_RELAXED, __HIP_MEMORY_SCOPE_AGENT);
            }
            // stage half A, MFMA half A (rb in flight), stage half B, MFMA half B
            #pragma unroll
            for (int i = 0; i < 2; ++i) {
                int j = tid + i * 256; int b = j >> 6, c = j & 63;
                unsigned int addr = (unsigned)(b * 1024 + c * 8) ^ (unsigned)((b & 7) << 4);
                *(u64*)(s_h + addr) = ra[i];
            }
            __syncthreads();
            #pragma unroll
            for (int kc = 0; kc < 8; ++kc) {
                bf16x8 a0 = *(const bf16x8*)(s_h + ((hO0 + kc * 64) ^ bS0));
                acc0 = __builtin_amdgcn_mfma_f32_16x16x32_bf16(a0, uBr[kc], acc0, 0, 0, 0);
            }
            #pragma unroll
            for (int i = 0; i < 2; ++i) {
                int j = tid + i * 256; int b = j >> 6, c = j & 63;
                unsigned int addr = (unsigned)(b * 1024 + 512 + c * 8) ^ (unsigned)((b & 7) << 4);
                *(u64*)(s_h + addr) = rb[i];
            }
            __syncthreads();
            #pragma unroll
            for (int kc = 8; kc < 16; ++kc) {
                bf16x8 a0 = *(const bf16x8*)(s_h + ((hO0 + kc * 64) ^ bS0));
                acc0 = __builtin_amdgcn_mfma_f32_16x16x32_bf16(a0, uBr[kc], acc0, 0, 0, 0);
            }
        }

        // C/D: row = h4*4+r (batch), col = n. Only rows 0..7 are real.
        if (h4 < 2) {
            #pragma unroll
            for (int r = 0; r < 4; ++r)
                s_S[h4 * 4 + r][n] = acc0[r];
        }
        __syncthreads();
        if (s_abort) return;

        float hv[2];
        if (tid < 64) {
            #pragma unroll
            for (int j = 0; j < 2; ++j) {
                int cx = ecp + j;
                float zi = s_S[eb][cx]      + s_bias[cx];
                float zf = s_S[eb][16 + cx] + s_bias[16 + cx];
                float zg = s_S[eb][32 + cx] + s_bias[32 + cx];
                float zo = s_S[eb][48 + cx] + s_bias[48 + cx];
                float ii = sigf(zi), ff = sigf(zf), gg = tanhfast(zg), oo = sigf(zo);
                float c = ff * c_reg[j] + ii * gg;
                c_reg[j] = c;
                hv[j] = oo * tanhfast(c);
            }
        }

        if (t == T_STEPS - 1) {
            if (tid < 64) {
                #pragma unroll
                for (int j = 0; j < 2; ++j) {
                    int col = c0 + ecp + j;
                    out[(size_t)(bo + eb) * 1024 + d * 512 + col] = hv[j];
                    out[32768 + d * 32768 + (size_t)(bo + eb) * 512 + col] = hv[j];
                    out[49152 + d * 32768 + (size_t)(bo + eb) * 512 + col] = c_reg[j];
                }
            }
            break;
        }

        // publish h(t+1)
        const int nb = (t + 1) & 1;
        if (tid < 64) {
            unsigned int hp = (unsigned)f2bf(hv[0]) | ((unsigned)f2bf(hv[1]) << 16);
            unsigned int slot = (unsigned)((grp * 2 + nb) * 2048 + eb * 256 + s * 8 + (tid & 7));
            if (isLocal) *((volatile unsigned int*)H32 + slot) = hp;
            else __hip_atomic_store(&H32[slot], hp, __ATOMIC_RELAXED, __HIP_MEMORY_SCOPE_AGENT);
        }
        __syncthreads();   // drains vmcnt: publishes acked before flag
        if (tid == 0) {
            if (isLocal) *(volatile unsigned int*)&flags[myFlag] = (unsigned)(t + 1);
            else __hip_atomic_store(&flags[myFlag], (unsigned)(t + 1), __ATOMIC_RELAXED, __HIP_MEMORY_SCOPE_AGENT);
        }

        // shadow: stage x(t+1), compute x@W
        {
            int t_x = d ? (T_STEPS - 2 - t) : (t + 1);
            const u64* xb = (const u64*)Xbf + (size_t)t_x * 2048;
            #pragma unroll
            for (int i = 0; i < 2; ++i) {
                int j = tid + i * 256; int b = j >> 6, c = j & 63;
                u64 v = xb[(bo + b) * 64 + c];
                unsigned int addr = (unsigned)(b * 512 + c * 8) ^ (unsigned)((b & 7) << 4);
                *(u64*)(s_x + addr) = v;
            }
        }
        __syncthreads();
        axc0 = f32x4{0.f, 0.f, 0.f, 0.f};
        #pragma unroll
        for (int kc = 0; kc < 8; ++kc) {
            bf16x8 a0 = *(const bf16x8*)(s_x + ((xO0 + kc * 64) ^ bS0));
            axc0 = __builtin_amdgcn_mfma_f32_16x16x32_bf16(a0, wBr[kc], axc0, 0, 0, 0);
        }
    }
}

extern "C" void kernel_launch(void* const* d_in, const int* in_sizes, int n_in,
                              void* d_out, int out_size, void* d_ws, size_t ws_size,
                              hipStream_t stream) {
    if (ws_size < WS_NEEDED) return;   // fail loudly via unwritten output

    const float* X   = (const float*)d_in[0];
    const float* W_f = (const float*)d_in[1];
    const float* U_f = (const float*)d_in[2];
    const float* b_f = (const float*)d_in[3];
    const float* W_b = (const float*)d_in[4];
    const float* U_b = (const float*)d_in[5];
    const float* b_b = (const float*)d_in[6];

    unsigned short* Xbf   = (unsigned short*)d_ws;
    unsigned int*   flags = (unsigned int*)((char*)d_ws + FLAGS_OFF);
    unsigned int*   xslot = (unsigned int*)((char*)d_ws + XSLOT_OFF);
    u64*            Hbuf  = (u64*)((char*)d_ws + HBUF_OFF);

    hipMemsetAsync(flags, 0, 2048, stream);   // flags + xslot zones
    prep_x<<<16384, 256, 0, stream>>>(X, Xbf);

    float* out = (float*)d_out;
    void* args[] = {(void*)&Xbf, (void*)&W_f, (void*)&U_f, (void*)&b_f,
                    (void*)&W_b, (void*)&U_b, (void*)&b_b,
                    (void*)&out, (void*)&flags, (void*)&xslot, (void*)&Hbuf};
    hipLaunchCooperativeKernel((void*)lstm_rec, dim3(NWG), dim3(256), args, 0, stream);
}

// Round 20
// 6241.491 us; speedup vs baseline: 1.1666x; 1.1666x over previous
//
#include <hip/hip_runtime.h>

#define T_STEPS 2048
#define NWG 64

typedef __bf16 bf16x8 __attribute__((ext_vector_type(8)));
typedef float f32x4 __attribute__((ext_vector_type(4)));
typedef unsigned long long u64;

// ws layout (identical to the proven R13/R16 kernel)
#define XBF_OFF   0ull                       // [2048][32][256] bf16 = 33554432 B
#define FLAGS_OFF 33554432ull                // 2 dirs x 32 packed u32 flags (4 KB zone)
#define HBUF_OFF  (FLAGS_OFF + 4096ull)      // [dir][buf][32][512] bf16 = 131072 B
#define WS_NEEDED (HBUF_OFF + 131072ull)

__device__ __forceinline__ unsigned short f2bf(float f) {
    unsigned int u = __builtin_bit_cast(unsigned int, f);
    u = u + 0x7fffu + ((u >> 16) & 1u);
    return (unsigned short)(u >> 16);
}
__device__ __forceinline__ float sigf(float x) { return 1.0f / (1.0f + __expf(-x)); }
__device__ __forceinline__ float tanhfast(float x) { return 1.0f - 2.0f / (__expf(2.0f * x) + 1.0f); }

// X: [32][2048][256] fp32 -> Xbf: [2048][32][256] bf16
__global__ void prep_x(const float* __restrict__ X, unsigned short* __restrict__ Xbf) {
    unsigned int idx = blockIdx.x * 256u + threadIdx.x;
    unsigned int k4 = idx & 63u;
    unsigned int b  = (idx >> 6) & 31u;
    unsigned int t  = idx >> 11;
    float4 v = *(const float4*)(X + ((size_t)b * 2048u + t) * 256u + k4 * 4u);
    u64 pk = (u64)f2bf(v.x)
           | ((u64)f2bf(v.y) << 16)
           | ((u64)f2bf(v.z) << 32)
           | ((u64)f2bf(v.w) << 48);
    *(u64*)(Xbf + ((size_t)t * 32u + b) * 256u + k4 * 4u) = pk;
}

// Persistent recurrent kernel: 64 WGs = 2 dirs x 32 slices (16 hidden cols each).
__global__ __launch_bounds__(256, 1) void lstm_rec(
    const unsigned short* __restrict__ Xbf,
    const float* __restrict__ W_f, const float* __restrict__ U_f, const float* __restrict__ b_f,
    const float* __restrict__ W_b, const float* __restrict__ U_b, const float* __restrict__ b_b,
    float* __restrict__ out, unsigned int* flags, unsigned int* Hbuf)
{
    const int wg = blockIdx.x;
    const int d  = wg >> 5;        // 0 = forward, 1 = backward
    const int s  = wg & 31;
    const int c0 = s * 16;
    const int tid = threadIdx.x;

    const float* Wm = d ? W_b : W_f;
    const float* Um = d ? U_b : U_f;
    const float* bia = d ? b_b : b_f;

    __shared__ __align__(16) unsigned char s_u[65536];   // U slice  [64 cols][512 k] bf16, swizzled
    __shared__ __align__(16) unsigned char s_w[32768];   // W slice  [64 cols][256 k] bf16, swizzled
    __shared__ __align__(16) unsigned char s_h[32768];   // H stage  [32 b][512 k]  bf16, swizzled
    __shared__ __align__(16) unsigned char s_x[16384];   // X stage  [32 b][256 k]  bf16, swizzled
    __shared__ float s_S[32][64];                        // gate pre-activations
    __shared__ float s_bias[64];
    __shared__ int s_abort;

    // ---- prologue: stage U/W slices (fp32 global -> bf16 LDS, XOR-swizzled) ----
    {
        int cl = tid & 15, g = (tid >> 4) & 3, k0 = tid >> 6;
        int n = g * 16 + cl;
        int gcol = g * 512 + c0 + cl;
        for (int i = 0; i < 128; ++i) {
            int k = k0 + i * 4;
            unsigned short v = f2bf(Um[(size_t)k * 2048 + gcol]);
            unsigned int addr = (unsigned)(n * 1024 + k * 2) ^ (unsigned)((n & 7) << 4);
            *(unsigned short*)(s_u + addr) = v;
        }
        for (int i = 0; i < 64; ++i) {
            int k = k0 + i * 4;
            unsigned short v = f2bf(Wm[(size_t)k * 2048 + gcol]);
            unsigned int addr = (unsigned)(n * 512 + k * 2) ^ (unsigned)((n & 7) << 4);
            *(unsigned short*)(s_w + addr) = v;
        }
        if (tid < 64) s_bias[tid] = bia[(tid >> 4) * 512 + c0 + (tid & 15)];
        if (tid == 0) s_abort = 0;
        // h0 = 0
        for (int i = 0; i < 16; ++i)
            *(u64*)(s_h + (tid + i * 256) * 8) = 0ull;
        // stage x for first step
        int t_x = d ? (T_STEPS - 1) : 0;
        const u64* xsrc = (const u64*)(Xbf + (size_t)t_x * 32 * 256);
        for (int i = 0; i < 8; ++i) {
            int ch = tid + i * 256;
            int b = ch >> 6;
            unsigned int addr = (unsigned)(ch * 8) ^ (unsigned)((b & 7) << 4);
            *(u64*)(s_x + addr) = xsrc[ch];
        }
    }
    __syncthreads();

    // per-thread MFMA addressing (16x16x32 bf16: A row = l&15, k = 8*(l>>4)+j)
    const int g  = tid >> 6;          // wave == gate
    const int l  = tid & 63;
    const int cl = l & 15;
    const int h4 = l >> 4;
    const int n  = g * 16 + cl;
    const unsigned int uO = (unsigned)(n * 1024 + h4 * 16);
    const unsigned int wO = (unsigned)(n * 512  + h4 * 16);
    const unsigned int nS = (unsigned)((n & 7) << 4);
    const int b0 = cl, b1 = cl + 16;
    const unsigned int hO0 = (unsigned)(b0 * 1024 + h4 * 16);
    const unsigned int hO1 = (unsigned)(b1 * 1024 + h4 * 16);
    const unsigned int xO0 = (unsigned)(b0 * 512  + h4 * 16);
    const unsigned int xO1 = (unsigned)(b1 * 512  + h4 * 16);
    const unsigned int bS0 = (unsigned)((b0 & 7) << 4);
    const unsigned int bS1 = (unsigned)((b1 & 7) << 4);

    // packed flags: one u32 per producer, 32 consecutive per dir (128B region;
    // unified poll: lanes 0..31 cover all 32 producers in one load)
    const unsigned int fBase  = (unsigned)(d * 32);
    const unsigned int myFlag = fBase + (unsigned)s;
    const unsigned int pollF  = fBase + (unsigned)(l & 31);

    // elementwise mapping
    const int eb  = tid >> 3;
    const int ecp = (tid & 7) * 2;
    float c_reg[2] = {0.f, 0.f};

    // ---- pin loop-invariant B fragments (U/W columns) in registers ----
    bf16x8 wBr[8];
    #pragma unroll
    for (int kc = 0; kc < 8; ++kc)
        wBr[kc] = *(const bf16x8*)(s_w + ((wO + kc * 64) ^ nS));
    bf16x8 uBr[16];
    #pragma unroll
    for (int kc = 0; kc < 16; ++kc)
        uBr[kc] = *(const bf16x8*)(s_u + ((uO + kc * 64) ^ nS));

    // ---- accX(0): x(0) @ W ----
    f32x4 axc0 = {0.f, 0.f, 0.f, 0.f};
    f32x4 axc1 = {0.f, 0.f, 0.f, 0.f};
    #pragma unroll
    for (int kc = 0; kc < 8; ++kc) {
        bf16x8 a0 = *(const bf16x8*)(s_x + ((xO0 + kc * 64) ^ bS0));
        bf16x8 a1 = *(const bf16x8*)(s_x + ((xO1 + kc * 64) ^ bS1));
        axc0 = __builtin_amdgcn_mfma_f32_16x16x32_bf16(a0, wBr[kc], axc0, 0, 0, 0);
        axc1 = __builtin_amdgcn_mfma_f32_16x16x32_bf16(a1, wBr[kc], axc1, 0, 0, 0);
    }

    for (int t = 0; t < T_STEPS; ++t) {
        f32x4 acc0 = axc0;
        f32x4 acc1 = axc1;

        if (t > 0) {
            u64* hsrc = (u64*)Hbuf + (size_t)(d * 2 + (t & 1)) * 4096;

            // ---- unified poll: all 32 producer flags in one coalesced load ----
            {
                unsigned int spin = 0;
                for (;;) {
                    unsigned int v = __hip_atomic_load(&flags[pollF], __ATOMIC_RELAXED, __HIP_MEMORY_SCOPE_AGENT);
                    if (__all((int)(v >= (unsigned)t))) break;
                    if (++spin > (1u << 21)) { s_abort = 1; break; }
                    if (spin > 64) __builtin_amdgcn_s_sleep(1);
                }
            }
            // ---- issue all 16 h-loads (coalesced 2KB runs per wave) ----
            u64 r[16];
            #pragma unroll
            for (int i = 0; i < 16; ++i) {
                int idx = tid + i * 256;               // 0..4095 covers [32 b][128 u64]
                r[i] = __hip_atomic_load(&hsrc[(idx >> 7) * 128 + (idx & 127)], __ATOMIC_RELAXED, __HIP_MEMORY_SCOPE_AGENT);
            }
            // ---- stage all to LDS, one barrier ----
            #pragma unroll
            for (int i = 0; i < 16; ++i) {
                int idx = tid + i * 256;
                int b = idx >> 7, c = idx & 127;
                unsigned int addr = (unsigned)(b * 1024 + c * 8) ^ (unsigned)((b & 7) << 4);
                *(u64*)(s_h + addr) = r[i];
            }
            __syncthreads();                   // h staged
            // ---- h @ U, 4 independent accumulator chains ----
            f32x4 aB0 = {0.f, 0.f, 0.f, 0.f};
            f32x4 aB1 = {0.f, 0.f, 0.f, 0.f};
            #pragma unroll
            for (int kc = 0; kc < 8; ++kc) {
                bf16x8 a0 = *(const bf16x8*)(s_h + ((hO0 + kc * 64) ^ bS0));
                bf16x8 a1 = *(const bf16x8*)(s_h + ((hO1 + kc * 64) ^ bS1));
                bf16x8 a2 = *(const bf16x8*)(s_h + ((hO0 + (kc + 8) * 64) ^ bS0));
                bf16x8 a3 = *(const bf16x8*)(s_h + ((hO1 + (kc + 8) * 64) ^ bS1));
                acc0 = __builtin_amdgcn_mfma_f32_16x16x32_bf16(a0, uBr[kc], acc0, 0, 0, 0);
                acc1 = __builtin_amdgcn_mfma_f32_16x16x32_bf16(a1, uBr[kc], acc1, 0, 0, 0);
                aB0  = __builtin_amdgcn_mfma_f32_16x16x32_bf16(a2, uBr[kc + 8], aB0, 0, 0, 0);
                aB1  = __builtin_amdgcn_mfma_f32_16x16x32_bf16(a3, uBr[kc + 8], aB1, 0, 0, 0);
            }
            acc0 = acc0 + aB0;
            acc1 = acc1 + aB1;
        }

        // C/D layout: row = h4*4+r, col = l&15
        #pragma unroll
        for (int r = 0; r < 4; ++r) {
            s_S[h4 * 4 + r][n]      = acc0[r];
            s_S[16 + h4 * 4 + r][n] = acc1[r];
        }
        __syncthreads();                       // gate exchange
        if (s_abort) return;                   // bounded-spin bailout

        float hv[2];
        #pragma unroll
        for (int j = 0; j < 2; ++j) {
            int cx = ecp + j;
            float zi = s_S[eb][cx]      + s_bias[cx];
            float zf = s_S[eb][16 + cx] + s_bias[16 + cx];
            float zg = s_S[eb][32 + cx] + s_bias[32 + cx];
            float zo = s_S[eb][48 + cx] + s_bias[48 + cx];
            float ii = sigf(zi), ff = sigf(zf), gg = tanhfast(zg), oo = sigf(zo);
            float c = ff * c_reg[j] + ii * gg;
            c_reg[j] = c;
            hv[j] = oo * tanhfast(c);
        }

        if (t == T_STEPS - 1) {
            #pragma unroll
            for (int j = 0; j < 2; ++j) {
                int col = c0 + ecp + j;
                out[(size_t)eb * 1024 + d * 512 + col] = hv[j];                 // merged
                out[32768 + d * 32768 + (size_t)eb * 512 + col] = hv[j];        // h_d
                out[49152 + d * 32768 + (size_t)eb * 512 + col] = c_reg[j];     // c_d
            }
            break;
        }

        // ---- publish h(t+1) (agent-scope stores to coherence point) ----
        const int nb = (t + 1) & 1;
        unsigned int hp = (unsigned)f2bf(hv[0]) | ((unsigned)f2bf(hv[1]) << 16);
        unsigned int hidx = (unsigned)((d * 2 + nb) * 8192 + eb * 256 + ((c0 + ecp) >> 1));
        __hip_atomic_store(&Hbuf[hidx], hp, __ATOMIC_RELAXED, __HIP_MEMORY_SCOPE_AGENT);

        // barrier drains each wave's vmcnt -> all publishes acked, then 1 flag store
        __syncthreads();
        if (tid == 0)
            __hip_atomic_store(&flags[myFlag], (unsigned)(t + 1), __ATOMIC_RELAXED, __HIP_MEMORY_SCOPE_AGENT);

        // ---- shadow: stage x(t+1), compute x@W for t+1 (off critical path) ----
        {
            int t_x = d ? (T_STEPS - 2 - t) : (t + 1);
            const u64* xsrc = (const u64*)(Xbf + (size_t)t_x * 32 * 256);
            #pragma unroll
            for (int i = 0; i < 8; ++i) {
                int ch = tid + i * 256;
                int b = ch >> 6;
                unsigned int addr = (unsigned)(ch * 8) ^ (unsigned)((b & 7) << 4);
                *(u64*)(s_x + addr) = xsrc[ch];
            }
        }
        __syncthreads();                       // s_x ready
        axc0 = f32x4{0.f, 0.f, 0.f, 0.f};
        axc1 = f32x4{0.f, 0.f, 0.f, 0.f};
        #pragma unroll
        for (int kc = 0; kc < 8; ++kc) {
            bf16x8 a0 = *(const bf16x8*)(s_x + ((xO0 + kc * 64) ^ bS0));
            bf16x8 a1 = *(const bf16x8*)(s_x + ((xO1 + kc * 64) ^ bS1));
            axc0 = __builtin_amdgcn_mfma_f32_16x16x32_bf16(a0, wBr[kc], axc0, 0, 0, 0);
            axc1 = __builtin_amdgcn_mfma_f32_16x16x32_bf16(a1, wBr[kc], axc1, 0, 0, 0);
        }
    }
}

extern "C" void kernel_launch(void* const* d_in, const int* in_sizes, int n_in,
                              void* d_out, int out_size, void* d_ws, size_t ws_size,
                              hipStream_t stream) {
    if (ws_size < WS_NEEDED) return;   // fail loudly via unwritten output

    const float* X   = (const float*)d_in[0];
    const float* W_f = (const float*)d_in[1];
    const float* U_f = (const float*)d_in[2];
    const float* b_f = (const float*)d_in[3];
    const float* W_b = (const float*)d_in[4];
    const float* U_b = (const float*)d_in[5];
    const float* b_b = (const float*)d_in[6];

    unsigned short* Xbf  = (unsigned short*)d_ws;
    unsigned int*  flags = (unsigned int*)((char*)d_ws + FLAGS_OFF);
    unsigned int*  Hbuf  = (unsigned int*)((char*)d_ws + HBUF_OFF);

    hipMemsetAsync(flags, 0, 4096, stream);
    prep_x<<<16384, 256, 0, stream>>>(X, Xbf);

    float* out = (float*)d_out;
    void* args[] = {(void*)&Xbf, (void*)&W_f, (void*)&U_f, (void*)&b_f,
                    (void*)&W_b, (void*)&U_b, (void*)&b_b,
                    (void*)&out, (void*)&flags, (void*)&Hbuf};
    hipLaunchCooperativeKernel((void*)lstm_rec, dim3(NWG), dim3(256), args, 0, stream);
}

// Round 21
// 6214.964 us; speedup vs baseline: 1.1715x; 1.0043x over previous
//
#include <hip/hip_runtime.h>

#define T_STEPS 2048
#define NWG 64

typedef __bf16 bf16x8 __attribute__((ext_vector_type(8)));
typedef float f32x4 __attribute__((ext_vector_type(4)));
typedef unsigned long long u64;

// ws layout (identical to the proven R13/R16/R20 kernel)
#define XBF_OFF   0ull                       // [2048][32][256] bf16 = 33554432 B
#define FLAGS_OFF 33554432ull                // 2 dirs x 32 packed u32 flags (4 KB zone)
#define HBUF_OFF  (FLAGS_OFF + 4096ull)      // [dir][buf][32][512] bf16 = 131072 B
#define WS_NEEDED (HBUF_OFF + 131072ull)

__device__ __forceinline__ unsigned short f2bf(float f) {
    unsigned int u = __builtin_bit_cast(unsigned int, f);
    u = u + 0x7fffu + ((u >> 16) & 1u);
    return (unsigned short)(u >> 16);
}
__device__ __forceinline__ float sigf(float x) { return 1.0f / (1.0f + __expf(-x)); }
__device__ __forceinline__ float tanhfast(float x) { return 1.0f - 2.0f / (__expf(2.0f * x) + 1.0f); }

// X: [32][2048][256] fp32 -> Xbf: [2048][32][256] bf16
__global__ void prep_x(const float* __restrict__ X, unsigned short* __restrict__ Xbf) {
    unsigned int idx = blockIdx.x * 256u + threadIdx.x;
    unsigned int k4 = idx & 63u;
    unsigned int b  = (idx >> 6) & 31u;
    unsigned int t  = idx >> 11;
    float4 v = *(const float4*)(X + ((size_t)b * 2048u + t) * 256u + k4 * 4u);
    u64 pk = (u64)f2bf(v.x)
           | ((u64)f2bf(v.y) << 16)
           | ((u64)f2bf(v.z) << 32)
           | ((u64)f2bf(v.w) << 48);
    *(u64*)(Xbf + ((size_t)t * 32u + b) * 256u + k4 * 4u) = pk;
}

// Persistent recurrent kernel: 64 WGs = 2 dirs x 32 slices (16 hidden cols each).
// R21: 16-slot XOR swizzle ((row&15)<<4) on all staged buffers + padded s_S.
__global__ __launch_bounds__(256, 1) void lstm_rec(
    const unsigned short* __restrict__ Xbf,
    const float* __restrict__ W_f, const float* __restrict__ U_f, const float* __restrict__ b_f,
    const float* __restrict__ W_b, const float* __restrict__ U_b, const float* __restrict__ b_b,
    float* __restrict__ out, unsigned int* flags, unsigned int* Hbuf)
{
    const int wg = blockIdx.x;
    const int d  = wg >> 5;        // 0 = forward, 1 = backward
    const int s  = wg & 31;
    const int c0 = s * 16;
    const int tid = threadIdx.x;

    const float* Wm = d ? W_b : W_f;
    const float* Um = d ? U_b : U_f;
    const float* bia = d ? b_b : b_f;

    __shared__ __align__(16) unsigned char s_u[65536];   // U slice  [64 cols][512 k] bf16, swizzled
    __shared__ __align__(16) unsigned char s_w[32768];   // W slice  [64 cols][256 k] bf16, swizzled
    __shared__ __align__(16) unsigned char s_h[32768];   // H stage  [32 b][512 k]  bf16, swizzled
    __shared__ __align__(16) unsigned char s_x[16384];   // X stage  [32 b][256 k]  bf16, swizzled
    __shared__ float s_S[32][68];                        // gate pre-activations (padded rows)
    __shared__ float s_bias[64];
    __shared__ int s_abort;

    // ---- prologue: stage U/W slices (fp32 global -> bf16 LDS, XOR-swizzled) ----
    {
        int cl = tid & 15, g = (tid >> 4) & 3, k0 = tid >> 6;
        int n = g * 16 + cl;
        int gcol = g * 512 + c0 + cl;
        for (int i = 0; i < 128; ++i) {
            int k = k0 + i * 4;
            unsigned short v = f2bf(Um[(size_t)k * 2048 + gcol]);
            unsigned int addr = (unsigned)(n * 1024 + k * 2) ^ (unsigned)((n & 15) << 4);
            *(unsigned short*)(s_u + addr) = v;
        }
        for (int i = 0; i < 64; ++i) {
            int k = k0 + i * 4;
            unsigned short v = f2bf(Wm[(size_t)k * 2048 + gcol]);
            unsigned int addr = (unsigned)(n * 512 + k * 2) ^ (unsigned)((n & 15) << 4);
            *(unsigned short*)(s_w + addr) = v;
        }
        if (tid < 64) s_bias[tid] = bia[(tid >> 4) * 512 + c0 + (tid & 15)];
        if (tid == 0) s_abort = 0;
        // h0 = 0 (zeros are swizzle-invariant)
        for (int i = 0; i < 16; ++i)
            *(u64*)(s_h + (tid + i * 256) * 8) = 0ull;
        // stage x for first step
        int t_x = d ? (T_STEPS - 1) : 0;
        const u64* xsrc = (const u64*)(Xbf + (size_t)t_x * 32 * 256);
        for (int i = 0; i < 8; ++i) {
            int ch = tid + i * 256;
            int b = ch >> 6;
            unsigned int addr = (unsigned)(ch * 8) ^ (unsigned)((b & 15) << 4);
            *(u64*)(s_x + addr) = xsrc[ch];
        }
    }
    __syncthreads();

    // per-thread MFMA addressing (16x16x32 bf16: A row = l&15, k = 8*(l>>4)+j)
    const int g  = tid >> 6;          // wave == gate
    const int l  = tid & 63;
    const int cl = l & 15;
    const int h4 = l >> 4;
    const int n  = g * 16 + cl;
    const unsigned int uO = (unsigned)(n * 1024 + h4 * 16);
    const unsigned int wO = (unsigned)(n * 512  + h4 * 16);
    const unsigned int nS = (unsigned)((n & 15) << 4);
    const int b0 = cl, b1 = cl + 16;
    const unsigned int hO0 = (unsigned)(b0 * 1024 + h4 * 16);
    const unsigned int hO1 = (unsigned)(b1 * 1024 + h4 * 16);
    const unsigned int xO0 = (unsigned)(b0 * 512  + h4 * 16);
    const unsigned int xO1 = (unsigned)(b1 * 512  + h4 * 16);
    const unsigned int bS0 = (unsigned)((b0 & 15) << 4);
    const unsigned int bS1 = (unsigned)((b1 & 15) << 4);

    // packed flags: one u32 per producer, 32 consecutive per dir (128B region;
    // unified poll: lanes 0..31 cover all 32 producers in one load)
    const unsigned int fBase  = (unsigned)(d * 32);
    const unsigned int myFlag = fBase + (unsigned)s;
    const unsigned int pollF  = fBase + (unsigned)(l & 31);

    // elementwise mapping
    const int eb  = tid >> 3;
    const int ecp = (tid & 7) * 2;
    float c_reg[2] = {0.f, 0.f};

    // ---- pin loop-invariant B fragments (U/W columns) in registers ----
    bf16x8 wBr[8];
    #pragma unroll
    for (int kc = 0; kc < 8; ++kc)
        wBr[kc] = *(const bf16x8*)(s_w + ((wO + kc * 64) ^ nS));
    bf16x8 uBr[16];
    #pragma unroll
    for (int kc = 0; kc < 16; ++kc)
        uBr[kc] = *(const bf16x8*)(s_u + ((uO + kc * 64) ^ nS));

    // ---- accX(0): x(0) @ W ----
    f32x4 axc0 = {0.f, 0.f, 0.f, 0.f};
    f32x4 axc1 = {0.f, 0.f, 0.f, 0.f};
    #pragma unroll
    for (int kc = 0; kc < 8; ++kc) {
        bf16x8 a0 = *(const bf16x8*)(s_x + ((xO0 + kc * 64) ^ bS0));
        bf16x8 a1 = *(const bf16x8*)(s_x + ((xO1 + kc * 64) ^ bS1));
        axc0 = __builtin_amdgcn_mfma_f32_16x16x32_bf16(a0, wBr[kc], axc0, 0, 0, 0);
        axc1 = __builtin_amdgcn_mfma_f32_16x16x32_bf16(a1, wBr[kc], axc1, 0, 0, 0);
    }

    for (int t = 0; t < T_STEPS; ++t) {
        f32x4 acc0 = axc0;
        f32x4 acc1 = axc1;

        if (t > 0) {
            u64* hsrc = (u64*)Hbuf + (size_t)(d * 2 + (t & 1)) * 4096;

            // ---- unified poll: all 32 producer flags in one coalesced load ----
            {
                unsigned int spin = 0;
                for (;;) {
                    unsigned int v = __hip_atomic_load(&flags[pollF], __ATOMIC_RELAXED, __HIP_MEMORY_SCOPE_AGENT);
                    if (__all((int)(v >= (unsigned)t))) break;
                    if (++spin > (1u << 21)) { s_abort = 1; break; }
                    if (spin > 64) __builtin_amdgcn_s_sleep(1);
                }
            }
            // ---- issue all 16 h-loads (coalesced 2KB runs per wave) ----
            u64 r[16];
            #pragma unroll
            for (int i = 0; i < 16; ++i) {
                int idx = tid + i * 256;               // 0..4095 covers [32 b][128 u64]
                r[i] = __hip_atomic_load(&hsrc[(idx >> 7) * 128 + (idx & 127)], __ATOMIC_RELAXED, __HIP_MEMORY_SCOPE_AGENT);
            }
            // ---- stage all to LDS, one barrier ----
            #pragma unroll
            for (int i = 0; i < 16; ++i) {
                int idx = tid + i * 256;
                int b = idx >> 7, c = idx & 127;
                unsigned int addr = (unsigned)(b * 1024 + c * 8) ^ (unsigned)((b & 15) << 4);
                *(u64*)(s_h + addr) = r[i];
            }
            __syncthreads();                   // h staged
            // ---- h @ U, 4 independent accumulator chains ----
            f32x4 aB0 = {0.f, 0.f, 0.f, 0.f};
            f32x4 aB1 = {0.f, 0.f, 0.f, 0.f};
            #pragma unroll
            for (int kc = 0; kc < 8; ++kc) {
                bf16x8 a0 = *(const bf16x8*)(s_h + ((hO0 + kc * 64) ^ bS0));
                bf16x8 a1 = *(const bf16x8*)(s_h + ((hO1 + kc * 64) ^ bS1));
                bf16x8 a2 = *(const bf16x8*)(s_h + ((hO0 + (kc + 8) * 64) ^ bS0));
                bf16x8 a3 = *(const bf16x8*)(s_h + ((hO1 + (kc + 8) * 64) ^ bS1));
                acc0 = __builtin_amdgcn_mfma_f32_16x16x32_bf16(a0, uBr[kc], acc0, 0, 0, 0);
                acc1 = __builtin_amdgcn_mfma_f32_16x16x32_bf16(a1, uBr[kc], acc1, 0, 0, 0);
                aB0  = __builtin_amdgcn_mfma_f32_16x16x32_bf16(a2, uBr[kc + 8], aB0, 0, 0, 0);
                aB1  = __builtin_amdgcn_mfma_f32_16x16x32_bf16(a3, uBr[kc + 8], aB1, 0, 0, 0);
            }
            acc0 = acc0 + aB0;
            acc1 = acc1 + aB1;
        }

        // C/D layout: row = h4*4+r, col = l&15
        #pragma unroll
        for (int r = 0; r < 4; ++r) {
            s_S[h4 * 4 + r][n]      = acc0[r];
            s_S[16 + h4 * 4 + r][n] = acc1[r];
        }
        __syncthreads();                       // gate exchange
        if (s_abort) return;                   // bounded-spin bailout

        float hv[2];
        #pragma unroll
        for (int j = 0; j < 2; ++j) {
            int cx = ecp + j;
            float zi = s_S[eb][cx]      + s_bias[cx];
            float zf = s_S[eb][16 + cx] + s_bias[16 + cx];
            float zg = s_S[eb][32 + cx] + s_bias[32 + cx];
            float zo = s_S[eb][48 + cx] + s_bias[48 + cx];
            float ii = sigf(zi), ff = sigf(zf), gg = tanhfast(zg), oo = sigf(zo);
            float c = ff * c_reg[j] + ii * gg;
            c_reg[j] = c;
            hv[j] = oo * tanhfast(c);
        }

        if (t == T_STEPS - 1) {
            #pragma unroll
            for (int j = 0; j < 2; ++j) {
                int col = c0 + ecp + j;
                out[(size_t)eb * 1024 + d * 512 + col] = hv[j];                 // merged
                out[32768 + d * 32768 + (size_t)eb * 512 + col] = hv[j];        // h_d
                out[49152 + d * 32768 + (size_t)eb * 512 + col] = c_reg[j];     // c_d
            }
            break;
        }

        // ---- publish h(t+1) (agent-scope stores to coherence point) ----
        const int nb = (t + 1) & 1;
        unsigned int hp = (unsigned)f2bf(hv[0]) | ((unsigned)f2bf(hv[1]) << 16);
        unsigned int hidx = (unsigned)((d * 2 + nb) * 8192 + eb * 256 + ((c0 + ecp) >> 1));
        __hip_atomic_store(&Hbuf[hidx], hp, __ATOMIC_RELAXED, __HIP_MEMORY_SCOPE_AGENT);

        // barrier drains each wave's vmcnt -> all publishes acked, then 1 flag store
        __syncthreads();
        if (tid == 0)
            __hip_atomic_store(&flags[myFlag], (unsigned)(t + 1), __ATOMIC_RELAXED, __HIP_MEMORY_SCOPE_AGENT);

        // ---- shadow: stage x(t+1), compute x@W for t+1 (off critical path) ----
        {
            int t_x = d ? (T_STEPS - 2 - t) : (t + 1);
            const u64* xsrc = (const u64*)(Xbf + (size_t)t_x * 32 * 256);
            #pragma unroll
            for (int i = 0; i < 8; ++i) {
                int ch = tid + i * 256;
                int b = ch >> 6;
                unsigned int addr = (unsigned)(ch * 8) ^ (unsigned)((b & 15) << 4);
                *(u64*)(s_x + addr) = xsrc[ch];
            }
        }
        __syncthreads();                       // s_x ready
        axc0 = f32x4{0.f, 0.f, 0.f, 0.f};
        axc1 = f32x4{0.f, 0.f, 0.f, 0.f};
        #pragma unroll
        for (int kc = 0; kc < 8; ++kc) {
            bf16x8 a0 = *(const bf16x8*)(s_x + ((xO0 + kc * 64) ^ bS0));
            bf16x8 a1 = *(const bf16x8*)(s_x + ((xO1 + kc * 64) ^ bS1));
            axc0 = __builtin_amdgcn_mfma_f32_16x16x32_bf16(a0, wBr[kc], axc0, 0, 0, 0);
            axc1 = __builtin_amdgcn_mfma_f32_16x16x32_bf16(a1, wBr[kc], axc1, 0, 0, 0);
        }
    }
}

extern "C" void kernel_launch(void* const* d_in, const int* in_sizes, int n_in,
                              void* d_out, int out_size, void* d_ws, size_t ws_size,
                              hipStream_t stream) {
    if (ws_size < WS_NEEDED) return;   // fail loudly via unwritten output

    const float* X   = (const float*)d_in[0];
    const float* W_f = (const float*)d_in[1];
    const float* U_f = (const float*)d_in[2];
    const float* b_f = (const float*)d_in[3];
    const float* W_b = (const float*)d_in[4];
    const float* U_b = (const float*)d_in[5];
    const float* b_b = (const float*)d_in[6];

    unsigned short* Xbf  = (unsigned short*)d_ws;
    unsigned int*  flags = (unsigned int*)((char*)d_ws + FLAGS_OFF);
    unsigned int*  Hbuf  = (unsigned int*)((char*)d_ws + HBUF_OFF);

    hipMemsetAsync(flags, 0, 4096, stream);
    prep_x<<<16384, 256, 0, stream>>>(X, Xbf);

    float* out = (float*)d_out;
    void* args[] = {(void*)&Xbf, (void*)&W_f, (void*)&U_f, (void*)&b_f,
                    (void*)&W_b, (void*)&U_b, (void*)&b_b,
                    (void*)&out, (void*)&flags, (void*)&Hbuf};
    hipLaunchCooperativeKernel((void*)lstm_rec, dim3(NWG), dim3(256), args, 0, stream);
}

// Round 23
// 6201.682 us; speedup vs baseline: 1.1741x; 1.0021x over previous
//
#include <hip/hip_runtime.h>

#define T_STEPS 2048
#define NWG 64

typedef __bf16 bf16x8 __attribute__((ext_vector_type(8)));
typedef float f32x4 __attribute__((ext_vector_type(4)));
typedef unsigned long long u64;

// ws layout (identical to the proven R13/R16/R20 kernel)
#define XBF_OFF   0ull                       // [2048][32][256] bf16 = 33554432 B
#define FLAGS_OFF 33554432ull                // 2 dirs x 32 packed u32 flags (4 KB zone)
#define HBUF_OFF  (FLAGS_OFF + 4096ull)      // [dir][buf][32][512] bf16 = 131072 B
#define WS_NEEDED (HBUF_OFF + 131072ull)

__device__ __forceinline__ unsigned short f2bf(float f) {
    unsigned int u = __builtin_bit_cast(unsigned int, f);
    u = u + 0x7fffu + ((u >> 16) & 1u);
    return (unsigned short)(u >> 16);
}
__device__ __forceinline__ float sigf(float x) { return 1.0f / (1.0f + __expf(-x)); }
__device__ __forceinline__ float tanhfast(float x) { return 1.0f - 2.0f / (__expf(2.0f * x) + 1.0f); }

// X: [32][2048][256] fp32 -> Xbf: [2048][32][256] bf16
__global__ void prep_x(const float* __restrict__ X, unsigned short* __restrict__ Xbf) {
    unsigned int idx = blockIdx.x * 256u + threadIdx.x;
    unsigned int k4 = idx & 63u;
    unsigned int b  = (idx >> 6) & 31u;
    unsigned int t  = idx >> 11;
    float4 v = *(const float4*)(X + ((size_t)b * 2048u + t) * 256u + k4 * 4u);
    u64 pk = (u64)f2bf(v.x)
           | ((u64)f2bf(v.y) << 16)
           | ((u64)f2bf(v.z) << 32)
           | ((u64)f2bf(v.w) << 48);
    *(u64*)(Xbf + ((size_t)t * 32u + b) * 256u + k4 * 4u) = pk;
}

// Persistent recurrent kernel: 64 WGs = 2 dirs x 32 slices (16 hidden cols each).
// R21 (proven): 16-slot XOR swizzle ((row&15)<<4) on all staged buffers + padded s_S.
__global__ __launch_bounds__(256, 1) void lstm_rec(
    const unsigned short* __restrict__ Xbf,
    const float* __restrict__ W_f, const float* __restrict__ U_f, const float* __restrict__ b_f,
    const float* __restrict__ W_b, const float* __restrict__ U_b, const float* __restrict__ b_b,
    float* __restrict__ out, unsigned int* flags, unsigned int* Hbuf)
{
    const int wg = blockIdx.x;
    const int d  = wg >> 5;        // 0 = forward, 1 = backward
    const int s  = wg & 31;
    const int c0 = s * 16;
    const int tid = threadIdx.x;

    const float* Wm = d ? W_b : W_f;
    const float* Um = d ? U_b : U_f;
    const float* bia = d ? b_b : b_f;

    __shared__ __align__(16) unsigned char s_u[65536];   // U slice  [64 cols][512 k] bf16, swizzled
    __shared__ __align__(16) unsigned char s_w[32768];   // W slice  [64 cols][256 k] bf16, swizzled
    __shared__ __align__(16) unsigned char s_h[32768];   // H stage  [32 b][512 k]  bf16, swizzled
    __shared__ __align__(16) unsigned char s_x[16384];   // X stage  [32 b][256 k]  bf16, swizzled
    __shared__ float s_S[32][68];                        // gate pre-activations (padded rows)
    __shared__ float s_bias[64];
    __shared__ int s_abort;

    // ---- prologue: stage U/W slices (fp32 global -> bf16 LDS, XOR-swizzled) ----
    {
        int cl = tid & 15, g = (tid >> 4) & 3, k0 = tid >> 6;
        int n = g * 16 + cl;
        int gcol = g * 512 + c0 + cl;
        for (int i = 0; i < 128; ++i) {
            int k = k0 + i * 4;
            unsigned short v = f2bf(Um[(size_t)k * 2048 + gcol]);
            unsigned int addr = (unsigned)(n * 1024 + k * 2) ^ (unsigned)((n & 15) << 4);
            *(unsigned short*)(s_u + addr) = v;
        }
        for (int i = 0; i < 64; ++i) {
            int k = k0 + i * 4;
            unsigned short v = f2bf(Wm[(size_t)k * 2048 + gcol]);
            unsigned int addr = (unsigned)(n * 512 + k * 2) ^ (unsigned)((n & 15) << 4);
            *(unsigned short*)(s_w + addr) = v;
        }
        if (tid < 64) s_bias[tid] = bia[(tid >> 4) * 512 + c0 + (tid & 15)];
        if (tid == 0) s_abort = 0;
        // h0 = 0 (zeros are swizzle-invariant)
        for (int i = 0; i < 16; ++i)
            *(u64*)(s_h + (tid + i * 256) * 8) = 0ull;
        // stage x for first step
        int t_x = d ? (T_STEPS - 1) : 0;
        const u64* xsrc = (const u64*)(Xbf + (size_t)t_x * 32 * 256);
        for (int i = 0; i < 8; ++i) {
            int ch = tid + i * 256;
            int b = ch >> 6;
            unsigned int addr = (unsigned)(ch * 8) ^ (unsigned)((b & 15) << 4);
            *(u64*)(s_x + addr) = xsrc[ch];
        }
    }
    __syncthreads();

    // per-thread MFMA addressing (16x16x32 bf16: A row = l&15, k = 8*(l>>4)+j)
    const int g  = tid >> 6;          // wave == gate
    const int l  = tid & 63;
    const int cl = l & 15;
    const int h4 = l >> 4;
    const int n  = g * 16 + cl;
    const unsigned int uO = (unsigned)(n * 1024 + h4 * 16);
    const unsigned int wO = (unsigned)(n * 512  + h4 * 16);
    const unsigned int nS = (unsigned)((n & 15) << 4);
    const int b0 = cl, b1 = cl + 16;
    const unsigned int hO0 = (unsigned)(b0 * 1024 + h4 * 16);
    const unsigned int hO1 = (unsigned)(b1 * 1024 + h4 * 16);
    const unsigned int xO0 = (unsigned)(b0 * 512  + h4 * 16);
    const unsigned int xO1 = (unsigned)(b1 * 512  + h4 * 16);
    const unsigned int bS0 = (unsigned)((b0 & 15) << 4);
    const unsigned int bS1 = (unsigned)((b1 & 15) << 4);

    // packed flags: one u32 per producer, 32 consecutive per dir (128B region;
    // unified poll: lanes 0..31 cover all 32 producers in one load)
    const unsigned int fBase  = (unsigned)(d * 32);
    const unsigned int myFlag = fBase + (unsigned)s;
    const unsigned int pollF  = fBase + (unsigned)(l & 31);

    // elementwise mapping
    const int eb  = tid >> 3;
    const int ecp = (tid & 7) * 2;
    float c_reg[2] = {0.f, 0.f};

    // ---- pin loop-invariant B fragments (U/W columns) in registers ----
    bf16x8 wBr[8];
    #pragma unroll
    for (int kc = 0; kc < 8; ++kc)
        wBr[kc] = *(const bf16x8*)(s_w + ((wO + kc * 64) ^ nS));
    bf16x8 uBr[16];
    #pragma unroll
    for (int kc = 0; kc < 16; ++kc)
        uBr[kc] = *(const bf16x8*)(s_u + ((uO + kc * 64) ^ nS));

    // ---- accX(0): x(0) @ W ----
    f32x4 axc0 = {0.f, 0.f, 0.f, 0.f};
    f32x4 axc1 = {0.f, 0.f, 0.f, 0.f};
    #pragma unroll
    for (int kc = 0; kc < 8; ++kc) {
        bf16x8 a0 = *(const bf16x8*)(s_x + ((xO0 + kc * 64) ^ bS0));
        bf16x8 a1 = *(const bf16x8*)(s_x + ((xO1 + kc * 64) ^ bS1));
        axc0 = __builtin_amdgcn_mfma_f32_16x16x32_bf16(a0, wBr[kc], axc0, 0, 0, 0);
        axc1 = __builtin_amdgcn_mfma_f32_16x16x32_bf16(a1, wBr[kc], axc1, 0, 0, 0);
    }

    for (int t = 0; t < T_STEPS; ++t) {
        f32x4 acc0 = axc0;
        f32x4 acc1 = axc1;

        if (t > 0) {
            u64* hsrc = (u64*)Hbuf + (size_t)(d * 2 + (t & 1)) * 4096;

            // ---- unified poll: all 32 producer flags in one coalesced load ----
            {
                unsigned int spin = 0;
                for (;;) {
                    unsigned int v = __hip_atomic_load(&flags[pollF], __ATOMIC_RELAXED, __HIP_MEMORY_SCOPE_AGENT);
                    if (__all((int)(v >= (unsigned)t))) break;
                    if (++spin > (1u << 21)) { s_abort = 1; break; }
                    if (spin > 64) __builtin_amdgcn_s_sleep(1);
                }
            }
            // ---- issue all 16 h-loads (coalesced 2KB runs per wave) ----
            u64 r[16];
            #pragma unroll
            for (int i = 0; i < 16; ++i) {
                int idx = tid + i * 256;               // 0..4095 covers [32 b][128 u64]
                r[i] = __hip_atomic_load(&hsrc[(idx >> 7) * 128 + (idx & 127)], __ATOMIC_RELAXED, __HIP_MEMORY_SCOPE_AGENT);
            }
            // ---- stage all to LDS, one barrier ----
            #pragma unroll
            for (int i = 0; i < 16; ++i) {
                int idx = tid + i * 256;
                int b = idx >> 7, c = idx & 127;
                unsigned int addr = (unsigned)(b * 1024 + c * 8) ^ (unsigned)((b & 15) << 4);
                *(u64*)(s_h + addr) = r[i];
            }
            __syncthreads();                   // h staged
            // ---- h @ U, 4 independent accumulator chains ----
            f32x4 aB0 = {0.f, 0.f, 0.f, 0.f};
            f32x4 aB1 = {0.f, 0.f, 0.f, 0.f};
            #pragma unroll
            for (int kc = 0; kc < 8; ++kc) {
                bf16x8 a0 = *(const bf16x8*)(s_h + ((hO0 + kc * 64) ^ bS0));
                bf16x8 a1 = *(const bf16x8*)(s_h + ((hO1 + kc * 64) ^ bS1));
                bf16x8 a2 = *(const bf16x8*)(s_h + ((hO0 + (kc + 8) * 64) ^ bS0));
                bf16x8 a3 = *(const bf16x8*)(s_h + ((hO1 + (kc + 8) * 64) ^ bS1));
                acc0 = __builtin_amdgcn_mfma_f32_16x16x32_bf16(a0, uBr[kc], acc0, 0, 0, 0);
                acc1 = __builtin_amdgcn_mfma_f32_16x16x32_bf16(a1, uBr[kc], acc1, 0, 0, 0);
                aB0  = __builtin_amdgcn_mfma_f32_16x16x32_bf16(a2, uBr[kc + 8], aB0, 0, 0, 0);
                aB1  = __builtin_amdgcn_mfma_f32_16x16x32_bf16(a3, uBr[kc + 8], aB1, 0, 0, 0);
            }
            acc0 = acc0 + aB0;
            acc1 = acc1 + aB1;
        }

        // C/D layout: row = h4*4+r, col = l&15
        #pragma unroll
        for (int r = 0; r < 4; ++r) {
            s_S[h4 * 4 + r][n]      = acc0[r];
            s_S[16 + h4 * 4 + r][n] = acc1[r];
        }
        __syncthreads();                       // gate exchange
        if (s_abort) return;                   // bounded-spin bailout

        float hv[2];
        #pragma unroll
        for (int j = 0; j < 2; ++j) {
            int cx = ecp + j;
            float zi = s_S[eb][cx]      + s_bias[cx];
            float zf = s_S[eb][16 + cx] + s_bias[16 + cx];
            float zg = s_S[eb][32 + cx] + s_bias[32 + cx];
            float zo = s_S[eb][48 + cx] + s_bias[48 + cx];
            float ii = sigf(zi), ff = sigf(zf), gg = tanhfast(zg), oo = sigf(zo);
            float c = ff * c_reg[j] + ii * gg;
            c_reg[j] = c;
            hv[j] = oo * tanhfast(c);
        }

        if (t == T_STEPS - 1) {
            #pragma unroll
            for (int j = 0; j < 2; ++j) {
                int col = c0 + ecp + j;
                out[(size_t)eb * 1024 + d * 512 + col] = hv[j];                 // merged
                out[32768 + d * 32768 + (size_t)eb * 512 + col] = hv[j];        // h_d
                out[49152 + d * 32768 + (size_t)eb * 512 + col] = c_reg[j];     // c_d
            }
            break;
        }

        // ---- publish h(t+1) (agent-scope stores to coherence point) ----
        const int nb = (t + 1) & 1;
        unsigned int hp = (unsigned)f2bf(hv[0]) | ((unsigned)f2bf(hv[1]) << 16);
        unsigned int hidx = (unsigned)((d * 2 + nb) * 8192 + eb * 256 + ((c0 + ecp) >> 1));
        __hip_atomic_store(&Hbuf[hidx], hp, __ATOMIC_RELAXED, __HIP_MEMORY_SCOPE_AGENT);

        // barrier drains each wave's vmcnt -> all publishes acked, then 1 flag store
        __syncthreads();
        if (tid == 0)
            __hip_atomic_store(&flags[myFlag], (unsigned)(t + 1), __ATOMIC_RELAXED, __HIP_MEMORY_SCOPE_AGENT);

        // ---- shadow: stage x(t+1), compute x@W for t+1 (off critical path) ----
        {
            int t_x = d ? (T_STEPS - 2 - t) : (t + 1);
            const u64* xsrc = (const u64*)(Xbf + (size_t)t_x * 32 * 256);
            #pragma unroll
            for (int i = 0; i < 8; ++i) {
                int ch = tid + i * 256;
                int b = ch >> 6;
                unsigned int addr = (unsigned)(ch * 8) ^ (unsigned)((b & 15) << 4);
                *(u64*)(s_x + addr) = xsrc[ch];
            }
        }
        __syncthreads();                       // s_x ready
        axc0 = f32x4{0.f, 0.f, 0.f, 0.f};
        axc1 = f32x4{0.f, 0.f, 0.f, 0.f};
        #pragma unroll
        for (int kc = 0; kc < 8; ++kc) {
            bf16x8 a0 = *(const bf16x8*)(s_x + ((xO0 + kc * 64) ^ bS0));
            bf16x8 a1 = *(const bf16x8*)(s_x + ((xO1 + kc * 64) ^ bS1));
            axc0 = __builtin_amdgcn_mfma_f32_16x16x32_bf16(a0, wBr[kc], axc0, 0, 0, 0);
            axc1 = __builtin_amdgcn_mfma_f32_16x16x32_bf16(a1, wBr[kc], axc1, 0, 0, 0);
        }
    }
}

extern "C" void kernel_launch(void* const* d_in, const int* in_sizes, int n_in,
                              void* d_out, int out_size, void* d_ws, size_t ws_size,
                              hipStream_t stream) {
    if (ws_size < WS_NEEDED) return;   // fail loudly via unwritten output

    const float* X   = (const float*)d_in[0];
    const float* W_f = (const float*)d_in[1];
    const float* U_f = (const float*)d_in[2];
    const float* b_f = (const float*)d_in[3];
    const float* W_b = (const float*)d_in[4];
    const float* U_b = (const float*)d_in[5];
    const float* b_b = (const float*)d_in[6];

    unsigned short* Xbf  = (unsigned short*)d_ws;
    unsigned int*  flags = (unsigned int*)((char*)d_ws + FLAGS_OFF);
    unsigned int*  Hbuf  = (unsigned int*)((char*)d_ws + HBUF_OFF);

    hipMemsetAsync(flags, 0, 4096, stream);
    prep_x<<<16384, 256, 0, stream>>>(X, Xbf);

    float* out = (float*)d_out;
    void* args[] = {(void*)&Xbf, (void*)&W_f, (void*)&U_f, (void*)&b_f,
                    (void*)&W_b, (void*)&U_b, (void*)&b_b,
                    (void*)&out, (void*)&flags, (void*)&Hbuf};
    hipLaunchCooperativeKernel((void*)lstm_rec, dim3(NWG), dim3(256), args, 0, stream);
}